// Round 12
// baseline (92.073 us; speedup 1.0000x reference)
//
#include <hip/hip_runtime.h>
#include <hip/hip_bf16.h>

#define MTOK 16384
#define DDIM 2048
#define NEXP 8
#define RNK 16
#define NC 128          // E*R down-projection columns
#define NW 160          // padded GEMM1 N: 128 h + 8 logits + 24 zero pad
#define LOGIT0 128
#define KSPLIT 2
#define KLEN (DDIM / KSPLIT)   // 1024
#define NT (KLEN / 64)         // 16 K-steps of 64

typedef __attribute__((ext_vector_type(8))) short bf16x8;
typedef __attribute__((ext_vector_type(4))) short short4v;
typedef __attribute__((ext_vector_type(4))) float f32x4;

typedef __attribute__((address_space(1))) const void gv_t;
typedef __attribute__((address_space(3))) void lv_t;

__device__ __forceinline__ short f2b(float f) {
  unsigned u = __float_as_uint(f);
  u += 0x7fffu + ((u >> 16) & 1u);   // round-to-nearest-even
  return (short)(u >> 16);
}
__device__ __forceinline__ float b2f(short s) {
  return __uint_as_float(((unsigned)(unsigned short)s) << 16);
}

// ---------------- K0: weight prep (fp32 -> bf16, round-6 layouts) ----------
// WdT pre-swizzled per 64-elem K-tile: linear 16B-slot s holds logical slot
// s^(n&7) -> linear global_load_lds + swizzled ds_read_b128 is conflict-free.
// Logical WdT[n][k]: n<128 -> down[n>>4][k][n&15]; 128..135 -> rw[n-128][k]; else 0
// UT[c][j]: up[j>>4][j&15][c]  (B-operand N x K for gemm2)
__global__ __launch_bounds__(256) void prep_k(const float* __restrict__ rw,
                                              const float* __restrict__ down,
                                              const float* __restrict__ up,
                                              short* __restrict__ WdT,
                                              short* __restrict__ UT) {
  int i = blockIdx.x * 256 + threadIdx.x;
  const int NWD = NW * DDIM;          // 327680
  const int NUT = DDIM * NC;          // 262144
  if (i < NWD) {
    int n = i / DDIM, k = i % DDIM;
    int s = (k >> 3) & 7;
    int src_k = (k & ~0x3F) | ((s ^ (n & 7)) << 3) | (k & 7);
    float v = 0.f;
    if (n < NC)             v = down[((n >> 4) * DDIM + src_k) * RNK + (n & 15)];
    else if (n < NC + NEXP) v = rw[(n - NC) * DDIM + src_k];
    WdT[i] = f2b(v);
  } else if (i < NWD + NUT) {
    int u = i - NWD;
    int c = u >> 7, j = u & 127;
    UT[u] = f2b(up[((j >> 4) * RNK + (j & 15)) * DDIM + c]);
  }
}

// ---------------- K1: GEMM1  Hp[ks][16384][160] (bf16) = X @ W^T -----------
// Round-6 verbatim (best measured): split-K=2, BM=64, counted-vmcnt 2-deep.
__global__ __launch_bounds__(256, 4) void gemm1_k(const float* __restrict__ X,
                                                  const short* __restrict__ WdT,
                                                  short* __restrict__ Hp) {
  __shared__ short Al[2][64][72];      // 18432 B (+8 pad)
  __shared__ short Bl[2][160 * 64];    // 40960 B, linear for global_load_lds
  const int tid = threadIdx.x;
  const int lane = tid & 63;
  const int w = tid >> 6;
  const int gm0 = blockIdx.x * 64;
  const int ks = blockIdx.y;
  const int kb = ks * KLEN;
  const int wr = (w & 1) * 32;         // wave row base
  const int wc = (w >> 1) * 80;        // wave col base (5 frags of 16)
  const int lr = lane & 15;
  const int lk = (lane >> 4) * 8;

  f32x4 acc[2][5];
#pragma unroll
  for (int m = 0; m < 2; ++m)
#pragma unroll
    for (int n = 0; n < 5; ++n) acc[m][n] = (f32x4){0.f, 0.f, 0.f, 0.f};

  float4 aR[2][4];   // two A staging sets (2 K-steps in flight)

  auto loadA = [&](int k0, int s) {
#pragma unroll
    for (int i2 = 0; i2 < 4; ++i2) {
      int f = tid + 256 * i2;
      int row = f >> 4, c4 = f & 15;
      aR[s][i2] = *(const float4*)(X + (size_t)(gm0 + row) * DDIM + k0 + c4 * 4);
    }
  };
  auto issueB = [&](int buf, int k0) {
#pragma unroll
    for (int j = 0; j < 5; ++j) {
      int u = (w * 5 + j) * 64 + lane;
      const short* g = WdT + (size_t)(u >> 3) * DDIM + k0 + (u & 7) * 8;
      short* l = &Bl[buf][(w * 5 + j) * 512];   // wave-uniform base
      __builtin_amdgcn_global_load_lds((gv_t*)g, (lv_t*)l, 16, 0, 0);
    }
  };
  auto writeA = [&](int buf, int s) {
#pragma unroll
    for (int i2 = 0; i2 < 4; ++i2) {
      int f = tid + 256 * i2;
      int row = f >> 4, c4 = f & 15;
      short4v v;
      v.x = f2b(aR[s][i2].x); v.y = f2b(aR[s][i2].y);
      v.z = f2b(aR[s][i2].z); v.w = f2b(aR[s][i2].w);
      *(short4v*)&Al[buf][row][c4 * 4] = v;
    }
  };
  auto compute = [&](int buf) {
#pragma unroll
    for (int kk2 = 0; kk2 < 2; ++kk2) {
      const int kk = kk2 * 32;
      bf16x8 a[2], b[5];
#pragma unroll
      for (int m = 0; m < 2; ++m)
        a[m] = *(const bf16x8*)&Al[buf][wr + m * 16 + lr][kk + lk];
#pragma unroll
      for (int n = 0; n < 5; ++n) {
        int row = wc + n * 16 + lr;
        int sl = ((kk >> 3) + (lane >> 4)) ^ (row & 7);   // swizzled 16B slot
        b[n] = *(const bf16x8*)&Bl[buf][row * 64 + sl * 8];
      }
#pragma unroll
      for (int m = 0; m < 2; ++m)
#pragma unroll
        for (int n = 0; n < 5; ++n)
          acc[m][n] = __builtin_amdgcn_mfma_f32_16x16x32_bf16(a[m], b[n], acc[m][n], 0, 0, 0);
    }
  };

  // ---- prologue: establish steady state (outstanding = A(1)2 + B(1)5) ----
  loadA(kb, 0);            // A(0): 2 loads
  issueB(0, kb);           // B(0): 5 gload_lds
  loadA(kb + 64, 1);       // A(1): 2
  issueB(1, kb + 64);      // B(1): 5   -> 14 outstanding
  asm volatile("s_waitcnt vmcnt(12)" ::: "memory");   // A(0) retired
  __builtin_amdgcn_sched_barrier(0);
  writeA(0, 0);
  asm volatile("s_waitcnt vmcnt(7)" ::: "memory");    // B(0) retired
  asm volatile("s_waitcnt lgkmcnt(0)" ::: "memory");
  __builtin_amdgcn_sched_barrier(0);
  __builtin_amdgcn_s_barrier();

  // ---- main loop: fully unrolled, all buffer indices static ----
#pragma unroll
  for (int t = 0; t < NT; ++t) {
    if (t + 2 < NT) loadA(kb + (t + 2) * 64, t & 1);  // A(t+2) into free set
    compute(t & 1);
    asm volatile("s_waitcnt lgkmcnt(0)" ::: "memory");
    __builtin_amdgcn_s_barrier();                     // all waves done with buf t&1
    __builtin_amdgcn_sched_barrier(0);
    if (t + 2 < NT) issueB(t & 1, kb + (t + 2) * 64); // B(t+2) into just-freed buf
    if (t + 1 < NT) {
      if (t + 2 < NT)
        asm volatile("s_waitcnt vmcnt(7)" ::: "memory");  // retire A(t+1),B(t+1)
      else
        asm volatile("s_waitcnt vmcnt(0)" ::: "memory");  // tail
      __builtin_amdgcn_sched_barrier(0);
      writeA((t + 1) & 1, (t + 1) & 1);
      asm volatile("s_waitcnt lgkmcnt(0)" ::: "memory");
      __builtin_amdgcn_sched_barrier(0);
    }
    __builtin_amdgcn_s_barrier();                     // publish A(t+1), B(t+1)
  }

  short* Hq = Hp + (size_t)ks * MTOK * NW;
  const int cr = (lane >> 4) * 4;
#pragma unroll
  for (int m = 0; m < 2; ++m)
#pragma unroll
    for (int n = 0; n < 5; ++n)
#pragma unroll
      for (int r = 0; r < 4; ++r) {
        int row = gm0 + wr + m * 16 + cr + r;
        int col = wc + n * 16 + lr;
        Hq[(size_t)row * NW + col] = f2b(acc[m][n][r]);
      }
}

// ---------------- K2: GEMM2 + fused routing + residual ---------------------
// Out = X + ((Hp0+Hp1) * route_w) @ U.  BM=128, BN=64, K=128.
// Routing (sum logits, top2 softmax) recomputed per block; weights parked
// as bf16 in Al's unused cols 128..135 (LDS stays 52 KB -> 3 blocks/CU).
// T14: epilogue's X loads issued at kernel start, held in VGPRs.
__global__ __launch_bounds__(256) void gemm2_k(const short* __restrict__ Hp,
                                               const short* __restrict__ UT,
                                               const float* __restrict__ X,
                                               float* __restrict__ Out) {
  __shared__ short Al[128][136];   // cols 0..127: scaled h; 128..135: wv bf16
  __shared__ short Bl[64][136];
  const int tid = threadIdx.x;
  const int lane = tid & 63;
  const int w = tid >> 6;
  const int gm0 = blockIdx.x * 128;
  const int n0 = blockIdx.y * 64;
  const int lr = lane & 15;
  const int lk = (lane >> 4) * 8;
  const short* Hp1 = Hp + (size_t)MTOK * NW;

  // T14 early X prefetch (exact epilogue addresses), held across compute
  float4 xPf[8];
#pragma unroll
  for (int j = 0; j < 8; ++j) {
    int c = lane + 64 * j;
    int rl = c >> 4, c4 = c & 15;
    xPf[j] = *(const float4*)(X + (size_t)(gm0 + w * 32 + rl) * DDIM + n0 + c4 * 4);
  }

  // fused routing: per-row top2 softmax on summed split-K logits
  if (tid < 128) {
    int t = gm0 + tid;
    uint4 l0 = *(const uint4*)(Hp  + (size_t)t * NW + LOGIT0);
    uint4 l1 = *(const uint4*)(Hp1 + (size_t)t * NW + LOGIT0);
    const short* p0 = (const short*)&l0;
    const short* p1 = (const short*)&l1;
    float lgv[8];
#pragma unroll
    for (int e = 0; e < 8; ++e) lgv[e] = b2f(p0[e]) + b2f(p1[e]);
    float b0 = -1e30f, b1 = -1e30f;
    int i0 = 0, i1 = 0;
#pragma unroll
    for (int e = 0; e < 8; ++e) {
      float v = lgv[e];
      if (v > b0) { b1 = b0; i1 = i0; b0 = v; i0 = e; }   // lax.top_k tie-break
      else if (v > b1) { b1 = v; i1 = e; }
    }
    float ex = __expf(b1 - b0);
    float inv = 1.f / (1.f + ex);
#pragma unroll
    for (int e = 0; e < 8; ++e)
      Al[tid][128 + e] = f2b((e == i0) ? inv : ((e == i1) ? ex * inv : 0.f));
  }
  // stage B (UT), independent of routing
#pragma unroll
  for (int i = 0; i < 4; ++i) {
    int f = tid + 256 * i;         // 64 rows x 16 chunks
    int row = f >> 4, c8 = f & 15;
    *(uint4*)&Bl[row][c8 * 8] = *(const uint4*)(UT + (size_t)(n0 + row) * NC + c8 * 8);
  }
  __syncthreads();                 // routing weights visible

  // stage A: sum split-K h, scale by routing weight (cols 0..127 only)
#pragma unroll
  for (int i = 0; i < 8; ++i) {
    int f = tid + 256 * i;         // 128 rows x 16 chunks(16B)
    int row = f >> 4, c8 = f & 15;
    uint4 h0 = *(const uint4*)(Hp  + (size_t)(gm0 + row) * NW + c8 * 8);
    uint4 h1 = *(const uint4*)(Hp1 + (size_t)(gm0 + row) * NW + c8 * 8);
    const short* p0 = (const short*)&h0;
    const short* p1 = (const short*)&h1;
    float wgt = b2f(Al[row][128 + (c8 >> 1)]);   // expert = (c8*8)>>4
    short r[8];
#pragma unroll
    for (int e = 0; e < 8; ++e)
      r[e] = f2b((b2f(p0[e]) + b2f(p1[e])) * wgt);
    *(uint4*)&Al[row][c8 * 8] = *(uint4*)r;
  }
  __syncthreads();

  f32x4 acc[2][4];
#pragma unroll
  for (int m = 0; m < 2; ++m)
#pragma unroll
    for (int n = 0; n < 4; ++n) acc[m][n] = (f32x4){0.f, 0.f, 0.f, 0.f};

#pragma unroll
  for (int ks = 0; ks < 4; ++ks) {
    const int kk = ks * 32;
    bf16x8 a[2], b[4];
#pragma unroll
    for (int m = 0; m < 2; ++m) a[m] = *(const bf16x8*)&Al[w * 32 + m * 16 + lr][kk + lk];
#pragma unroll
    for (int n = 0; n < 4; ++n) b[n] = *(const bf16x8*)&Bl[n * 16 + lr][kk + lk];
#pragma unroll
    for (int m = 0; m < 2; ++m)
#pragma unroll
      for (int n = 0; n < 4; ++n)
        acc[m][n] = __builtin_amdgcn_mfma_f32_16x16x32_bf16(a[m], b[n], acc[m][n], 0, 0, 0);
  }

  // Epilogue: wave-private LDS transpose (Al rows [w*32,(w+1)*32) -- only
  // this wave read those rows as A-frags), then residual from xPf + store.
  float* eps = (float*)&Al[0][0] + w * 2176;   // 32 rows x 68 floats
  const int cr = (lane >> 4) * 4;
#pragma unroll
  for (int m = 0; m < 2; ++m)
#pragma unroll
    for (int n = 0; n < 4; ++n)
#pragma unroll
      for (int r = 0; r < 4; ++r)
        eps[(m * 16 + cr + r) * 68 + n * 16 + lr] = acc[m][n][r];

#pragma unroll
  for (int j = 0; j < 8; ++j) {
    int c = lane + 64 * j;         // 512 float4-chunks: 32 rows x 16
    int rl = c >> 4, c4 = c & 15;
    float4 v = *(const float4*)&eps[rl * 68 + c4 * 4];
    size_t idx = (size_t)(gm0 + w * 32 + rl) * DDIM + n0 + c4 * 4;
    v.x += xPf[j].x; v.y += xPf[j].y; v.z += xPf[j].z; v.w += xPf[j].w;
    *(float4*)(Out + idx) = v;
  }
}

// ---------------------------------------------------------------------------
extern "C" void kernel_launch(void* const* d_in, const int* in_sizes, int n_in,
                              void* d_out, int out_size, void* d_ws, size_t ws_size,
                              hipStream_t stream) {
  const float* x    = (const float*)d_in[0];
  const float* rw   = (const float*)d_in[1];
  const float* down = (const float*)d_in[2];
  const float* up   = (const float*)d_in[3];
  float* out = (float*)d_out;

  char* ws = (char*)d_ws;
  short* WdT = (short*)ws;                          // 160*2048*2    =   655360 B
  short* UT  = (short*)(ws + 655360);               // 2048*128*2    =   524288 B
  short* Hp  = (short*)(ws + 1179648);              // 2*16384*160*2 = 10485760 B
                                                    // total 11665408 B

  prep_k<<<2304, 256, 0, stream>>>(rw, down, up, WdT, UT);
  gemm1_k<<<dim3(MTOK / 64, KSPLIT), 256, 0, stream>>>(x, WdT, Hp);        // 512 blocks
  gemm2_k<<<dim3(MTOK / 128, DDIM / 64), 256, 0, stream>>>(Hp, UT, x, out); // 4096 blocks
}

// Round 14
// 80.980 us; speedup vs baseline: 1.1370x; 1.1370x over previous
//
#include <hip/hip_runtime.h>
#include <hip/hip_bf16.h>

#define MTOK 16384
#define DDIM 2048
#define NEXP 8
#define RNK 16
#define NC 128          // E*R down-projection columns
#define NW 160          // padded GEMM1 N: 128 h + 8 logits + 24 zero pad
#define LOGIT0 128
#define KSPLIT 2
#define KLEN (DDIM / KSPLIT)   // 1024
#define NT (KLEN / 64)         // 16 K-steps of 64

typedef __attribute__((ext_vector_type(8))) short bf16x8;
typedef __attribute__((ext_vector_type(4))) short short4v;
typedef __attribute__((ext_vector_type(4))) float f32x4;

typedef __attribute__((address_space(1))) const void gv_t;
typedef __attribute__((address_space(3))) void lv_t;

__device__ __forceinline__ short f2b(float f) {
  unsigned u = __float_as_uint(f);
  u += 0x7fffu + ((u >> 16) & 1u);   // round-to-nearest-even
  return (short)(u >> 16);
}
__device__ __forceinline__ float b2f(short s) {
  return __uint_as_float(((unsigned)(unsigned short)s) << 16);
}

// ---------------- K0: weight prep (fp32 -> bf16, round-6 layouts) ----------
// WdT pre-swizzled per 64-elem K-tile: linear 16B-slot s holds logical slot
// s^(n&7) -> linear global_load_lds + swizzled ds_read_b128 is conflict-free.
// Logical WdT[n][k]: n<128 -> down[n>>4][k][n&15]; 128..135 -> rw[n-128][k]; else 0
// UT[c][j]: up[j>>4][j&15][c]  (B-operand N x K for gemm2)
__global__ __launch_bounds__(256) void prep_k(const float* __restrict__ rw,
                                              const float* __restrict__ down,
                                              const float* __restrict__ up,
                                              short* __restrict__ WdT,
                                              short* __restrict__ UT) {
  int i = blockIdx.x * 256 + threadIdx.x;
  const int NWD = NW * DDIM;          // 327680
  const int NUT = DDIM * NC;          // 262144
  if (i < NWD) {
    int n = i / DDIM, k = i % DDIM;
    int s = (k >> 3) & 7;
    int src_k = (k & ~0x3F) | ((s ^ (n & 7)) << 3) | (k & 7);
    float v = 0.f;
    if (n < NC)             v = down[((n >> 4) * DDIM + src_k) * RNK + (n & 15)];
    else if (n < NC + NEXP) v = rw[(n - NC) * DDIM + src_k];
    WdT[i] = f2b(v);
  } else if (i < NWD + NUT) {
    int u = i - NWD;
    int c = u >> 7, j = u & 127;
    UT[u] = f2b(up[((j >> 4) * RNK + (j & 15)) * DDIM + c]);
  }
}

// ---------------- K1: GEMM1  Hp[ks][16384][160] (bf16) = X @ W^T -----------
// Round-6 verbatim (best measured): split-K=2, BM=64, counted-vmcnt 2-deep.
__global__ __launch_bounds__(256, 4) void gemm1_k(const float* __restrict__ X,
                                                  const short* __restrict__ WdT,
                                                  short* __restrict__ Hp) {
  __shared__ short Al[2][64][72];      // 18432 B (+8 pad)
  __shared__ short Bl[2][160 * 64];    // 40960 B, linear for global_load_lds
  const int tid = threadIdx.x;
  const int lane = tid & 63;
  const int w = tid >> 6;
  const int gm0 = blockIdx.x * 64;
  const int ks = blockIdx.y;
  const int kb = ks * KLEN;
  const int wr = (w & 1) * 32;         // wave row base
  const int wc = (w >> 1) * 80;        // wave col base (5 frags of 16)
  const int lr = lane & 15;
  const int lk = (lane >> 4) * 8;

  f32x4 acc[2][5];
#pragma unroll
  for (int m = 0; m < 2; ++m)
#pragma unroll
    for (int n = 0; n < 5; ++n) acc[m][n] = (f32x4){0.f, 0.f, 0.f, 0.f};

  float4 aR[2][4];   // two A staging sets (2 K-steps in flight)

  auto loadA = [&](int k0, int s) {
#pragma unroll
    for (int i2 = 0; i2 < 4; ++i2) {
      int f = tid + 256 * i2;
      int row = f >> 4, c4 = f & 15;
      aR[s][i2] = *(const float4*)(X + (size_t)(gm0 + row) * DDIM + k0 + c4 * 4);
    }
  };
  auto issueB = [&](int buf, int k0) {
#pragma unroll
    for (int j = 0; j < 5; ++j) {
      int u = (w * 5 + j) * 64 + lane;
      const short* g = WdT + (size_t)(u >> 3) * DDIM + k0 + (u & 7) * 8;
      short* l = &Bl[buf][(w * 5 + j) * 512];   // wave-uniform base
      __builtin_amdgcn_global_load_lds((gv_t*)g, (lv_t*)l, 16, 0, 0);
    }
  };
  auto writeA = [&](int buf, int s) {
#pragma unroll
    for (int i2 = 0; i2 < 4; ++i2) {
      int f = tid + 256 * i2;
      int row = f >> 4, c4 = f & 15;
      short4v v;
      v.x = f2b(aR[s][i2].x); v.y = f2b(aR[s][i2].y);
      v.z = f2b(aR[s][i2].z); v.w = f2b(aR[s][i2].w);
      *(short4v*)&Al[buf][row][c4 * 4] = v;
    }
  };
  auto compute = [&](int buf) {
#pragma unroll
    for (int kk2 = 0; kk2 < 2; ++kk2) {
      const int kk = kk2 * 32;
      bf16x8 a[2], b[5];
#pragma unroll
      for (int m = 0; m < 2; ++m)
        a[m] = *(const bf16x8*)&Al[buf][wr + m * 16 + lr][kk + lk];
#pragma unroll
      for (int n = 0; n < 5; ++n) {
        int row = wc + n * 16 + lr;
        int sl = ((kk >> 3) + (lane >> 4)) ^ (row & 7);   // swizzled 16B slot
        b[n] = *(const bf16x8*)&Bl[buf][row * 64 + sl * 8];
      }
#pragma unroll
      for (int m = 0; m < 2; ++m)
#pragma unroll
        for (int n = 0; n < 5; ++n)
          acc[m][n] = __builtin_amdgcn_mfma_f32_16x16x32_bf16(a[m], b[n], acc[m][n], 0, 0, 0);
    }
  };

  // ---- prologue: establish steady state (outstanding = A(1)2 + B(1)5) ----
  loadA(kb, 0);            // A(0): 2 loads
  issueB(0, kb);           // B(0): 5 gload_lds
  loadA(kb + 64, 1);       // A(1): 2
  issueB(1, kb + 64);      // B(1): 5   -> 14 outstanding
  asm volatile("s_waitcnt vmcnt(12)" ::: "memory");   // A(0) retired
  __builtin_amdgcn_sched_barrier(0);
  writeA(0, 0);
  asm volatile("s_waitcnt vmcnt(7)" ::: "memory");    // B(0) retired
  asm volatile("s_waitcnt lgkmcnt(0)" ::: "memory");
  __builtin_amdgcn_sched_barrier(0);
  __builtin_amdgcn_s_barrier();

  // ---- main loop: fully unrolled, all buffer indices static ----
#pragma unroll
  for (int t = 0; t < NT; ++t) {
    if (t + 2 < NT) loadA(kb + (t + 2) * 64, t & 1);  // A(t+2) into free set
    compute(t & 1);
    asm volatile("s_waitcnt lgkmcnt(0)" ::: "memory");
    __builtin_amdgcn_s_barrier();                     // all waves done with buf t&1
    __builtin_amdgcn_sched_barrier(0);
    if (t + 2 < NT) issueB(t & 1, kb + (t + 2) * 64); // B(t+2) into just-freed buf
    if (t + 1 < NT) {
      if (t + 2 < NT)
        asm volatile("s_waitcnt vmcnt(7)" ::: "memory");  // retire A(t+1),B(t+1)
      else
        asm volatile("s_waitcnt vmcnt(0)" ::: "memory");  // tail
      __builtin_amdgcn_sched_barrier(0);
      writeA((t + 1) & 1, (t + 1) & 1);
      asm volatile("s_waitcnt lgkmcnt(0)" ::: "memory");
      __builtin_amdgcn_sched_barrier(0);
    }
    __builtin_amdgcn_s_barrier();                     // publish A(t+1), B(t+1)
  }

  short* Hq = Hp + (size_t)ks * MTOK * NW;
  const int cr = (lane >> 4) * 4;
#pragma unroll
  for (int m = 0; m < 2; ++m)
#pragma unroll
    for (int n = 0; n < 5; ++n)
#pragma unroll
      for (int r = 0; r < 4; ++r) {
        int row = gm0 + wr + m * 16 + cr + r;
        int col = wc + n * 16 + lr;
        Hq[(size_t)row * NW + col] = f2b(acc[m][n][r]);
      }
}

// ---------------- K2: GEMM2 + routing (once) + residual --------------------
// 512 blocks: block = (mb = bid&127 -> 128 rows, q = bid>>7 -> 512 cols).
// Routing + split-K sum + scale staged ONCE; A-frags hoisted to registers;
// 8 n-tiles reuse them. Out via nontemporal stores (don't evict X from L3).
__global__ __launch_bounds__(256, 2) void gemm2m_k(const short* __restrict__ Hp,
                                                   const short* __restrict__ UT,
                                                   const float* __restrict__ X,
                                                   float* __restrict__ Out) {
  __shared__ short Bl[64][136];    // 17408 B, B tile
  __shared__ short At[128][136];   // 34816 B: scaled A + wv; later eps scratch
  const int tid = threadIdx.x;
  const int lane = tid & 63;
  const int w = tid >> 6;
  const int mb = blockIdx.x & 127, q = blockIdx.x >> 7;
  const int gm0 = mb * 128;
  const int nbase = q * 512;
  const int lr = lane & 15;
  const int lk = (lane >> 4) * 8;
  const short* Hp1 = Hp + (size_t)MTOK * NW;

  // routing: per-row top2 softmax on summed split-K logits -> At[:,128..135]
  if (tid < 128) {
    int t = gm0 + tid;
    uint4 l0 = *(const uint4*)(Hp  + (size_t)t * NW + LOGIT0);
    uint4 l1 = *(const uint4*)(Hp1 + (size_t)t * NW + LOGIT0);
    const short* p0 = (const short*)&l0;
    const short* p1 = (const short*)&l1;
    float lgv[8];
#pragma unroll
    for (int e = 0; e < 8; ++e) lgv[e] = b2f(p0[e]) + b2f(p1[e]);
    float b0 = -1e30f, b1 = -1e30f;
    int i0 = 0, i1 = 0;
#pragma unroll
    for (int e = 0; e < 8; ++e) {
      float v = lgv[e];
      if (v > b0) { b1 = b0; i1 = i0; b0 = v; i0 = e; }   // lax.top_k tie-break
      else if (v > b1) { b1 = v; i1 = e; }
    }
    float ex = __expf(b1 - b0);
    float inv = 1.f / (1.f + ex);
#pragma unroll
    for (int e = 0; e < 8; ++e)
      At[tid][128 + e] = f2b((e == i0) ? inv : ((e == i1) ? ex * inv : 0.f));
  }
  __syncthreads();

  // stage A once: sum split-K h, scale by routing weight (cols 0..127)
#pragma unroll
  for (int i = 0; i < 8; ++i) {
    int f = tid + 256 * i;         // 128 rows x 16 chunks(16B)
    int row = f >> 4, c8 = f & 15;
    uint4 h0 = *(const uint4*)(Hp  + (size_t)(gm0 + row) * NW + c8 * 8);
    uint4 h1 = *(const uint4*)(Hp1 + (size_t)(gm0 + row) * NW + c8 * 8);
    const short* p0 = (const short*)&h0;
    const short* p1 = (const short*)&h1;
    float wgt = b2f(At[row][128 + (c8 >> 1)]);   // expert = (c8*8)>>4
    short r[8];
#pragma unroll
    for (int e = 0; e < 8; ++e)
      r[e] = f2b((b2f(p0[e]) + b2f(p1[e])) * wgt);
    *(uint4*)&At[row][c8 * 8] = *(uint4*)r;
  }
  __syncthreads();

  // hoist A-frags to registers (each wave: rows w*32..w*32+32, all K=128)
  bf16x8 af[2][4];
#pragma unroll
  for (int m = 0; m < 2; ++m)
#pragma unroll
    for (int kc = 0; kc < 4; ++kc)
      af[m][kc] = *(const bf16x8*)&At[w * 32 + m * 16 + lr][kc * 32 + lk];
  __syncthreads();                 // At now free -> epilogue scratch

  float* eps = (float*)&At[0][0] + w * 2176;   // wave-private 32 x 68 floats
  const int cr = (lane >> 4) * 4;

#pragma unroll 1
  for (int it = 0; it < 8; ++it) {
    const int n0 = nbase + it * 64;
    // T14: X prefetch for this tile (held in VGPRs across compute)
    float4 xPf[8];
#pragma unroll
    for (int j = 0; j < 8; ++j) {
      int c = lane + 64 * j;
      int rl = c >> 4, c4 = c & 15;
      xPf[j] = *(const float4*)(X + (size_t)(gm0 + w * 32 + rl) * DDIM + n0 + c4 * 4);
    }
    // stage B tile
#pragma unroll
    for (int i = 0; i < 4; ++i) {
      int f = tid + 256 * i;       // 64 rows x 16 chunks
      int row = f >> 4, c8 = f & 15;
      *(uint4*)&Bl[row][c8 * 8] = *(const uint4*)(UT + (size_t)(n0 + row) * NC + c8 * 8);
    }
    __syncthreads();

    f32x4 acc[2][4];
#pragma unroll
    for (int m = 0; m < 2; ++m)
#pragma unroll
      for (int n = 0; n < 4; ++n) acc[m][n] = (f32x4){0.f, 0.f, 0.f, 0.f};
#pragma unroll
    for (int kc = 0; kc < 4; ++kc) {
      bf16x8 b[4];
#pragma unroll
      for (int n = 0; n < 4; ++n) b[n] = *(const bf16x8*)&Bl[n * 16 + lr][kc * 32 + lk];
#pragma unroll
      for (int m = 0; m < 2; ++m)
#pragma unroll
        for (int n = 0; n < 4; ++n)
          acc[m][n] = __builtin_amdgcn_mfma_f32_16x16x32_bf16(af[m][kc], b[n], acc[m][n], 0, 0, 0);
    }

    // wave-private transpose -> f32x4 residual + NONTEMPORAL store
#pragma unroll
    for (int m = 0; m < 2; ++m)
#pragma unroll
      for (int n = 0; n < 4; ++n)
#pragma unroll
        for (int r = 0; r < 4; ++r)
          eps[(m * 16 + cr + r) * 68 + n * 16 + lr] = acc[m][n][r];
#pragma unroll
    for (int j = 0; j < 8; ++j) {
      int c = lane + 64 * j;
      int rl = c >> 4, c4 = c & 15;
      f32x4 v = *(const f32x4*)&eps[rl * 68 + c4 * 4];
      size_t idx = (size_t)(gm0 + w * 32 + rl) * DDIM + n0 + c4 * 4;
      v[0] += xPf[j].x; v[1] += xPf[j].y; v[2] += xPf[j].z; v[3] += xPf[j].w;
      __builtin_nontemporal_store(v, (f32x4*)(Out + idx));
    }
    __syncthreads();               // Bl safe to restage
  }
}

// ---------------------------------------------------------------------------
extern "C" void kernel_launch(void* const* d_in, const int* in_sizes, int n_in,
                              void* d_out, int out_size, void* d_ws, size_t ws_size,
                              hipStream_t stream) {
  const float* x    = (const float*)d_in[0];
  const float* rw   = (const float*)d_in[1];
  const float* down = (const float*)d_in[2];
  const float* up   = (const float*)d_in[3];
  float* out = (float*)d_out;

  char* ws = (char*)d_ws;
  short* WdT = (short*)ws;                          // 160*2048*2    =   655360 B
  short* UT  = (short*)(ws + 655360);               // 2048*128*2    =   524288 B
  short* Hp  = (short*)(ws + 1179648);              // 2*16384*160*2 = 10485760 B
                                                    // total 11665408 B

  prep_k<<<2304, 256, 0, stream>>>(rw, down, up, WdT, UT);
  gemm1_k<<<dim3(MTOK / 64, KSPLIT), 256, 0, stream>>>(x, WdT, Hp);   // 512 blocks
  gemm2m_k<<<512, 256, 0, stream>>>(Hp, UT, x, out);                  // 512 blocks
}